// Round 14
// baseline (33.629 us; speedup 1.0000x reference)
//
#include <hip/hip_runtime.h>
#include <math.h>

#define BLK 100          // BLOCK
#define NF  128          // N_freqs
#define NTOT (NF * BLK)  // 12800
#define P   104          // LDS pitch (floats): rows 16B-aligned (416B)
#define NT  512          // 8 waves = 2 waves/SIMD (measured best)

__device__ __forceinline__ float4 fnma4(float4 v, float s, const float4 p) {
    v.x -= s * p.x; v.y -= s * p.y; v.z -= s * p.z; v.w -= s * p.w; return v;
}
__device__ __forceinline__ float4 mul4(float4 v, float s) {
    v.x *= s; v.y *= s; v.z *= s; v.w *= s; return v;
}

#define LD4(r, c4) (*reinterpret_cast<float4*>(&a[(r) * P + 4 * (c4)]))

// Factor the 8x8 panel at rows kb..kb+7 (columns = groups q2, q2+1); lane
// column group gg. Produces Q0..Q7 = panel^-1 * P_raw (per-lane), updates
// mant/e2/lneg with the 8 diagonal values. Pure per-lane ops, no barriers.
#define PANEL_Q8(kb, q2)                                                        \
    {                                                                           \
        float4 pA0 = LD4((kb)+0, (q2)), pB0 = LD4((kb)+0, (q2)+1);              \
        float4 pA1 = LD4((kb)+1, (q2)), pB1 = LD4((kb)+1, (q2)+1);              \
        float4 pA2 = LD4((kb)+2, (q2)), pB2 = LD4((kb)+2, (q2)+1);              \
        float4 pA3 = LD4((kb)+3, (q2)), pB3 = LD4((kb)+3, (q2)+1);              \
        float4 pA4 = LD4((kb)+4, (q2)), pB4 = LD4((kb)+4, (q2)+1);              \
        float4 pA5 = LD4((kb)+5, (q2)), pB5 = LD4((kb)+5, (q2)+1);              \
        float4 pA6 = LD4((kb)+6, (q2)), pB6 = LD4((kb)+6, (q2)+1);              \
        float4 pA7 = LD4((kb)+7, (q2)), pB7 = LD4((kb)+7, (q2)+1);              \
        float4 P0 = LD4((kb)+0, gg), P1 = LD4((kb)+1, gg);                      \
        float4 P2 = LD4((kb)+2, gg), P3 = LD4((kb)+3, gg);                      \
        float4 P4 = LD4((kb)+4, gg), P5 = LD4((kb)+5, gg);                      \
        float4 P6 = LD4((kb)+6, gg), P7 = LD4((kb)+7, gg);                      \
        const float d0 = pA0.x, r0 = 1.0f / d0;                                 \
        float l;                                                                \
        l = pA1.x*r0; pA1=fnma4(pA1,l,pA0); pB1=fnma4(pB1,l,pB0); P1=fnma4(P1,l,P0); \
        l = pA2.x*r0; pA2=fnma4(pA2,l,pA0); pB2=fnma4(pB2,l,pB0); P2=fnma4(P2,l,P0); \
        l = pA3.x*r0; pA3=fnma4(pA3,l,pA0); pB3=fnma4(pB3,l,pB0); P3=fnma4(P3,l,P0); \
        l = pA4.x*r0; pA4=fnma4(pA4,l,pA0); pB4=fnma4(pB4,l,pB0); P4=fnma4(P4,l,P0); \
        l = pA5.x*r0; pA5=fnma4(pA5,l,pA0); pB5=fnma4(pB5,l,pB0); P5=fnma4(P5,l,P0); \
        l = pA6.x*r0; pA6=fnma4(pA6,l,pA0); pB6=fnma4(pB6,l,pB0); P6=fnma4(P6,l,P0); \
        l = pA7.x*r0; pA7=fnma4(pA7,l,pA0); pB7=fnma4(pB7,l,pB0); P7=fnma4(P7,l,P0); \
        const float d1 = pA1.y, r1 = 1.0f / d1;                                 \
        l = pA2.y*r1; pA2=fnma4(pA2,l,pA1); pB2=fnma4(pB2,l,pB1); P2=fnma4(P2,l,P1); \
        l = pA3.y*r1; pA3=fnma4(pA3,l,pA1); pB3=fnma4(pB3,l,pB1); P3=fnma4(P3,l,P1); \
        l = pA4.y*r1; pA4=fnma4(pA4,l,pA1); pB4=fnma4(pB4,l,pB1); P4=fnma4(P4,l,P1); \
        l = pA5.y*r1; pA5=fnma4(pA5,l,pA1); pB5=fnma4(pB5,l,pB1); P5=fnma4(P5,l,P1); \
        l = pA6.y*r1; pA6=fnma4(pA6,l,pA1); pB6=fnma4(pB6,l,pB1); P6=fnma4(P6,l,P1); \
        l = pA7.y*r1; pA7=fnma4(pA7,l,pA1); pB7=fnma4(pB7,l,pB1); P7=fnma4(P7,l,P1); \
        const float d2 = pA2.z, r2 = 1.0f / d2;                                 \
        l = pA3.z*r2; pA3=fnma4(pA3,l,pA2); pB3=fnma4(pB3,l,pB2); P3=fnma4(P3,l,P2); \
        l = pA4.z*r2; pA4=fnma4(pA4,l,pA2); pB4=fnma4(pB4,l,pB2); P4=fnma4(P4,l,P2); \
        l = pA5.z*r2; pA5=fnma4(pA5,l,pA2); pB5=fnma4(pB5,l,pB2); P5=fnma4(P5,l,P2); \
        l = pA6.z*r2; pA6=fnma4(pA6,l,pA2); pB6=fnma4(pB6,l,pB2); P6=fnma4(P6,l,P2); \
        l = pA7.z*r2; pA7=fnma4(pA7,l,pA2); pB7=fnma4(pB7,l,pB2); P7=fnma4(P7,l,P2); \
        const float d3 = pA3.w, r3 = 1.0f / d3;                                 \
        l = pA4.w*r3; pB4=fnma4(pB4,l,pB3); P4=fnma4(P4,l,P3);                  \
        l = pA5.w*r3; pB5=fnma4(pB5,l,pB3); P5=fnma4(P5,l,P3);                  \
        l = pA6.w*r3; pB6=fnma4(pB6,l,pB3); P6=fnma4(P6,l,P3);                  \
        l = pA7.w*r3; pB7=fnma4(pB7,l,pB3); P7=fnma4(P7,l,P3);                  \
        const float d4 = pB4.x, r4 = 1.0f / d4;                                 \
        l = pB5.x*r4; pB5=fnma4(pB5,l,pB4); P5=fnma4(P5,l,P4);                  \
        l = pB6.x*r4; pB6=fnma4(pB6,l,pB4); P6=fnma4(P6,l,P4);                  \
        l = pB7.x*r4; pB7=fnma4(pB7,l,pB4); P7=fnma4(P7,l,P4);                  \
        const float d5 = pB5.y, r5 = 1.0f / d5;                                 \
        l = pB6.y*r5; pB6=fnma4(pB6,l,pB5); P6=fnma4(P6,l,P5);                  \
        l = pB7.y*r5; pB7=fnma4(pB7,l,pB5); P7=fnma4(P7,l,P5);                  \
        const float d6 = pB6.z, r6 = 1.0f / d6;                                 \
        l = pB7.z*r6; pB7=fnma4(pB7,l,pB6); P7=fnma4(P7,l,P6);                  \
        const float d7 = pB7.w, r7 = 1.0f / d7;                                 \
        Q7 = mul4(P7, r7);                                                      \
        Q6 = mul4(fnma4(P6, pB6.w, Q7), r6);                                    \
        Q5 = mul4(fnma4(fnma4(P5, pB5.z, Q6), pB5.w, Q7), r5);                  \
        Q4 = mul4(fnma4(fnma4(fnma4(P4, pB4.y, Q5), pB4.z, Q6), pB4.w, Q7), r4); \
        Q3 = mul4(fnma4(fnma4(fnma4(fnma4(P3, pB3.x, Q4), pB3.y, Q5), pB3.z, Q6), pB3.w, Q7), r3); \
        Q2 = mul4(fnma4(fnma4(fnma4(fnma4(fnma4(P2, pA2.w, Q3), pB2.x, Q4), pB2.y, Q5), pB2.z, Q6), pB2.w, Q7), r2); \
        Q1 = mul4(fnma4(fnma4(fnma4(fnma4(fnma4(fnma4(P1, pA1.z, Q2), pA1.w, Q3), pB1.x, Q4), pB1.y, Q5), pB1.z, Q6), pB1.w, Q7), r1); \
        Q0 = mul4(fnma4(fnma4(fnma4(fnma4(fnma4(fnma4(fnma4(P0, pA0.y, Q1), pA0.z, Q2), pA0.w, Q3), pB0.x, Q4), pB0.y, Q5), pB0.z, Q6), pB0.w, Q7), r0); \
        mant *= d0 * d1 * d2 * d3; { int t_; mant = frexpf(mant, &t_); e2 += t_; } \
        mant *= d4 * d5 * d6 * d7; { int t_; mant = frexpf(mant, &t_); e2 += t_; } \
        lneg += (d0<0.0f)+(d1<0.0f)+(d2<0.0f)+(d3<0.0f)+(d4<0.0f)+(d5<0.0f)+(d6<0.0f)+(d7<0.0f); \
    }

// One workgroup (512 thr) per frequency block. Rank-8 blocked non-pivoted LU
// in LDS, 1 barrier/phase (12 phases + prologue), producer/consumer split:
//   wave 0: urgent-sweep rows k0+8..k0+15 with reg-resident Q(k0), factor
//     panel(k0+8) -> Q(k0+8), publish to qbuf (double-buffered). Last phase
//     factors the 4-row tail (rows 96-99) for diagonals only.
//   waves 1-7: load Q(k0), bulk-sweep rows k0+16..99 over 14 streams.
// No column masking in sweeps: dead-column updates are harmless L-math.
__global__ __launch_bounds__(NT, 2) void lu_logdet_kernel(const float* __restrict__ w,
                                                          const float* __restrict__ L,
                                                          float* __restrict__ out) {
    __shared__ float  a[BLK * P];
    __shared__ float4 qbuf[2][8][26];

    const int f    = blockIdx.x;
    const int tid  = threadIdx.x;
    const int wave = tid >> 6;
    const int sid  = tid >> 5;       // 16 half-wave streams
    const int g    = tid & 31;       // float4 column group
    const int gg   = (g < 25) ? g : 24;

    // ---- load diag block f, fused transform: M[r][c] = s_r*D[r][c] + (r==c ? 1-s_r : 0)
    const float* base = L + (size_t)f * BLK * NTOT + (size_t)f * BLK;
    for (int q = tid; q < BLK * 25; q += NT) {         // 25 float4 per row
        const int r  = q / 25;
        const int c0 = (q - r * 25) * 4;
        const float4 v = *reinterpret_cast<const float4*>(base + (size_t)r * NTOT + c0);
        const float sv = 1.0f / (1.0f + expf(-w[f * BLK + r]));
        const float ds = 1.0f - sv;
        float4 m;
        m.x = sv * v.x + ((c0 + 0) == r ? ds : 0.0f);
        m.y = sv * v.y + ((c0 + 1) == r ? ds : 0.0f);
        m.z = sv * v.z + ((c0 + 2) == r ? ds : 0.0f);
        m.w = sv * v.w + ((c0 + 3) == r ? ds : 0.0f);
        *reinterpret_cast<float4*>(&a[r * P + c0]) = m;
    }
    __syncthreads();

    float mant = 1.0f;
    int   e2   = 0;
    int   lneg = 0;
    float4 Q0, Q1, Q2, Q3, Q4, Q5, Q6, Q7;

    // ---- prologue: everyone computes Q(0) redundantly
    PANEL_Q8(0, 0)

    for (int k0 = 0; k0 <= 88; k0 += 8) {
        const int pc = k0 >> 2;          // pan column groups pc, pc+1
        const int b  = (k0 >> 3) & 1;
        const int nb = b ^ 1;

        if (wave == 0) {
            __builtin_amdgcn_s_setprio(1);
            // ---- urgent sweep: rows k0+8..k0+15 (sid0: +8..11, sid1: +12..15)
            if (g < 25) {
                const int rbase = k0 + 8 + ((sid & 1) << 2);
                #pragma unroll
                for (int j = 0; j < 4; ++j) {
                    const int r = rbase + j;
                    if (r < BLK) {
                        const float4 pA = LD4(r, pc);      // uniform per half-wave
                        const float4 pB = LD4(r, pc + 1);
                        float4 v = LD4(r, g);
                        v = fnma4(v, pA.x, Q0); v = fnma4(v, pA.y, Q1);
                        v = fnma4(v, pA.z, Q2); v = fnma4(v, pA.w, Q3);
                        v = fnma4(v, pB.x, Q4); v = fnma4(v, pB.y, Q5);
                        v = fnma4(v, pB.z, Q6); v = fnma4(v, pB.w, Q7);
                        LD4(r, g) = v;
                    }
                }
            }
            if (k0 < 88) {
                // ---- factor panel(k0+8) from rows this wave just swept
                PANEL_Q8(k0 + 8, pc + 2)
                if (g < 25) {
                    qbuf[nb][0][g] = Q0; qbuf[nb][1][g] = Q1;
                    qbuf[nb][2][g] = Q2; qbuf[nb][3][g] = Q3;
                    qbuf[nb][4][g] = Q4; qbuf[nb][5][g] = Q5;
                    qbuf[nb][6][g] = Q6; qbuf[nb][7][g] = Q7;
                }
            } else {
                // ---- tail: 4x4 panel rows 96..99 (cols group 24), diag only
                float4 t0 = LD4(96, 24), t1 = LD4(97, 24), t2 = LD4(98, 24), t3 = LD4(99, 24);
                const float d0 = t0.x, r0 = 1.0f / d0;
                float l;
                l = t1.x*r0; t1 = fnma4(t1, l, t0);
                l = t2.x*r0; t2 = fnma4(t2, l, t0);
                l = t3.x*r0; t3 = fnma4(t3, l, t0);
                const float d1 = t1.y, r1 = 1.0f / d1;
                l = t2.y*r1; t2 = fnma4(t2, l, t1);
                l = t3.y*r1; t3 = fnma4(t3, l, t1);
                const float d2 = t2.z, r2 = 1.0f / d2;
                l = t3.z*r2; t3 = fnma4(t3, l, t2);
                const float d3 = t3.w;
                mant *= d0 * d1 * d2 * d3;
                { int t_; mant = frexpf(mant, &t_); e2 += t_; }
                lneg += (d0<0.0f)+(d1<0.0f)+(d2<0.0f)+(d3<0.0f);
            }
            __builtin_amdgcn_s_setprio(0);
        } else {
            // ---- consumers: fetch Q(k0) (prologue regs at k0==0), bulk sweep
            if (k0 > 0) {
                Q0 = qbuf[b][0][gg]; Q1 = qbuf[b][1][gg];
                Q2 = qbuf[b][2][gg]; Q3 = qbuf[b][3][gg];
                Q4 = qbuf[b][4][gg]; Q5 = qbuf[b][5][gg];
                Q6 = qbuf[b][6][gg]; Q7 = qbuf[b][7][gg];
            }
            if (g < 25) {
                int i = k0 + 16 + (sid - 2);     // 14 streams
                for (; i + 14 < BLK; i += 28) {
                    const int i2 = i + 14;
                    const float4 pA1_ = LD4(i,  pc);
                    const float4 pB1_ = LD4(i,  pc + 1);
                    const float4 pA2_ = LD4(i2, pc);
                    const float4 pB2_ = LD4(i2, pc + 1);
                    float4 vA = LD4(i,  g);
                    float4 vB = LD4(i2, g);
                    vA = fnma4(vA, pA1_.x, Q0); vA = fnma4(vA, pA1_.y, Q1);
                    vA = fnma4(vA, pA1_.z, Q2); vA = fnma4(vA, pA1_.w, Q3);
                    vA = fnma4(vA, pB1_.x, Q4); vA = fnma4(vA, pB1_.y, Q5);
                    vA = fnma4(vA, pB1_.z, Q6); vA = fnma4(vA, pB1_.w, Q7);
                    vB = fnma4(vB, pA2_.x, Q0); vB = fnma4(vB, pA2_.y, Q1);
                    vB = fnma4(vB, pA2_.z, Q2); vB = fnma4(vB, pA2_.w, Q3);
                    vB = fnma4(vB, pB2_.x, Q4); vB = fnma4(vB, pB2_.y, Q5);
                    vB = fnma4(vB, pB2_.z, Q6); vB = fnma4(vB, pB2_.w, Q7);
                    LD4(i,  g) = vA;
                    LD4(i2, g) = vB;
                }
                for (; i < BLK; i += 14) {
                    const float4 pA = LD4(i, pc);
                    const float4 pB = LD4(i, pc + 1);
                    float4 v = LD4(i, g);
                    v = fnma4(v, pA.x, Q0); v = fnma4(v, pA.y, Q1);
                    v = fnma4(v, pA.z, Q2); v = fnma4(v, pA.w, Q3);
                    v = fnma4(v, pB.x, Q4); v = fnma4(v, pB.y, Q5);
                    v = fnma4(v, pB.z, Q6); v = fnma4(v, pB.w, Q7);
                    LD4(i, g) = v;
                }
            }
        }
        __syncthreads();
    }

    // ---- wave 0 lanes hold the full result redundantly; thread 0 publishes
    if (tid == 0) {
        float ld = logf(mant) + (float)e2 * 0.69314718055994531f;
        if ((lneg & 1) || !isfinite(ld)) ld = __int_as_float(0x7fc00000);  // NaN
        out[1 + f] = ld;
        atomicAdd(out, ld);   // out[0] zeroed via memset before launch; NaN propagates
    }
}

extern "C" void kernel_launch(void* const* d_in, const int* in_sizes, int n_in,
                              void* d_out, int out_size, void* d_ws, size_t ws_size,
                              hipStream_t stream) {
    const float* w = (const float*)d_in[0];   // weights (12800,) f32
    const float* L = (const float*)d_in[1];   // L_kernel (12800,12800) f32
    float* out = (float*)d_out;               // [0]=sum, [1..128]=logdets
    hipMemsetAsync(d_out, 0, sizeof(float), stream);   // zero the atomic accumulator
    lu_logdet_kernel<<<NF, NT, 0, stream>>>(w, L, out);
}

// Round 15
// 31.792 us; speedup vs baseline: 1.0578x; 1.0578x over previous
//
#include <hip/hip_runtime.h>
#include <math.h>

#define BLK 100          // BLOCK
#define NF  128          // N_freqs
#define NTOT (NF * BLK)  // 12800
#define P   104          // LDS pitch (floats): rows 16B-aligned (416B)
#define NT  512          // 8 waves = 2 waves/SIMD (measured best)

__device__ __forceinline__ float4 fnma4(float4 v, float s, const float4 p) {
    v.x -= s * p.x; v.y -= s * p.y; v.z -= s * p.z; v.w -= s * p.w; return v;
}
__device__ __forceinline__ float4 mul4(float4 v, float s) {
    v.x *= s; v.y *= s; v.z *= s; v.w *= s; return v;
}
__device__ __forceinline__ float rdl(float x, int l) {
    return __uint_as_float(__builtin_amdgcn_readlane(__float_as_uint(x), l));
}
__device__ __forceinline__ float4 swap32(float4 v) {
    float4 o;
    o.x = __shfl_xor(v.x, 32); o.y = __shfl_xor(v.y, 32);
    o.z = __shfl_xor(v.z, 32); o.w = __shfl_xor(v.w, 32);
    return o;
}

#define LD4(r, c4) (*reinterpret_cast<float4*>(&a[(r) * P + 4 * (c4)]))

// 4x4 panel factorization core: pp0..pp3 (panel col group, uniform scalars),
// P0..P3 (this lane's col group of the 4 pivot rows) -> Q0..Q3 = panel^-1 P,
// accumulates mant/e2/lneg. Pure per-lane ops.
#define PANEL_CORE()                                                           \
    {                                                                          \
        const float d0 = pp0.x, r0i = 1.0f / d0;                               \
        float l;                                                               \
        l = pp1.x * r0i;  pp1 = fnma4(pp1, l, pp0);  P1 = fnma4(P1, l, P0);    \
        const float d1 = pp1.y, r1i = 1.0f / d1;                               \
        l = pp2.x * r0i;  pp2 = fnma4(pp2, l, pp0);  P2 = fnma4(P2, l, P0);    \
        l = pp2.y * r1i;  pp2 = fnma4(pp2, l, pp1);  P2 = fnma4(P2, l, P1);    \
        const float d2 = pp2.z, r2i = 1.0f / d2;                               \
        l = pp3.x * r0i;  pp3 = fnma4(pp3, l, pp0);  P3 = fnma4(P3, l, P0);    \
        l = pp3.y * r1i;  pp3 = fnma4(pp3, l, pp1);  P3 = fnma4(P3, l, P1);    \
        l = pp3.z * r2i;  pp3 = fnma4(pp3, l, pp2);  P3 = fnma4(P3, l, P2);    \
        const float d3 = pp3.w, r3i = 1.0f / d3;                               \
        Q3 = mul4(P3, r3i);                                                    \
        Q2 = mul4(fnma4(P2, pp2.w, Q3), r2i);                                  \
        Q1 = mul4(fnma4(fnma4(P1, pp1.z, Q2), pp1.w, Q3), r1i);                \
        Q0 = mul4(fnma4(fnma4(fnma4(P0, pp0.y, Q1), pp0.z, Q2), pp0.w, Q3), r0i); \
        mant *= d0 * d1 * d2 * d3;                                             \
        { int t_; mant = frexpf(mant, &t_); e2 += t_; }                        \
        lneg += (d0 < 0.0f) + (d1 < 0.0f) + (d2 < 0.0f) + (d3 < 0.0f);         \
    }

#define SWEEP4(vv, pan)                                                        \
    vv = fnma4(vv, pan.x, Q0); vv = fnma4(vv, pan.y, Q1);                      \
    vv = fnma4(vv, pan.z, Q2); vv = fnma4(vv, pan.w, Q3);

// One workgroup (512 thr) per frequency block. Rank-4 blocked non-pivoted LU
// in LDS, 1 barrier/phase, producer/consumer split:
//   wave 0 (producer): urgent-sweeps rows k0+4..7 IN REGISTERS (no LDS
//     writeback -- those rows are dead afterward), exchanges halves via
//     shfl_xor(32), extracts pp via readlane at lane gp+1, factors the panel
//     entirely in registers -> Q(k0+4), publishes Q to qbuf (dbuffered).
//   waves 1-7 (consumers): load Q(k0), bulk-sweep rows k0+8..99 over 14
//     streams with a 4-deep software-pipelined unroll.
__global__ __launch_bounds__(NT) void lu_logdet_kernel(const float* __restrict__ w,
                                                       const float* __restrict__ L,
                                                       float* __restrict__ out) {
    __shared__ float  a[BLK * P];
    __shared__ float4 qbuf[2][4][26];

    const int f    = blockIdx.x;
    const int tid  = threadIdx.x;
    const int wave = tid >> 6;
    const int sid  = tid >> 5;       // 16 half-wave streams
    const int g    = tid & 31;       // float4 column group
    const int gg   = (g < 25) ? g : 24;
    const int h    = sid & 1;        // half within wave

    // ---- load diag block f, fused transform: M[r][c] = s_r*D[r][c] + (r==c ? 1-s_r : 0)
    const float* base = L + (size_t)f * BLK * NTOT + (size_t)f * BLK;
    for (int q = tid; q < BLK * 25; q += NT) {         // 25 float4 per row
        const int r  = q / 25;
        const int c0 = (q - r * 25) * 4;
        const float4 v = *reinterpret_cast<const float4*>(base + (size_t)r * NTOT + c0);
        const float sv = 1.0f / (1.0f + expf(-w[f * BLK + r]));
        const float ds = 1.0f - sv;
        float4 m;
        m.x = sv * v.x + ((c0 + 0) == r ? ds : 0.0f);
        m.y = sv * v.y + ((c0 + 1) == r ? ds : 0.0f);
        m.z = sv * v.z + ((c0 + 2) == r ? ds : 0.0f);
        m.w = sv * v.w + ((c0 + 3) == r ? ds : 0.0f);
        *reinterpret_cast<float4*>(&a[r * P + c0]) = m;
    }
    __syncthreads();

    float mant = 1.0f;
    int   e2   = 0;
    int   lneg = 0;
    float4 Q0, Q1, Q2, Q3;

    // ---- prologue: everyone computes Q(0) redundantly from LDS
    {
        float4 pp0 = LD4(0, 0), pp1 = LD4(1, 0), pp2 = LD4(2, 0), pp3 = LD4(3, 0);
        float4 P0 = LD4(0, gg), P1 = LD4(1, gg), P2 = LD4(2, gg), P3 = LD4(3, gg);
        PANEL_CORE()
    }

    for (int k0 = 0; k0 <= 92; k0 += 4) {
        const int gp = k0 >> 2;
        const int b  = gp & 1;
        const int nb = b ^ 1;

        if (wave == 0) {
            __builtin_amdgcn_s_setprio(1);
            // ---- urgent sweep rows k0+4..7 in registers (no writeback)
            const int i1 = k0 + 4 + h;           // half0: k0+4, half1: k0+5
            const int i2 = k0 + 6 + h;           // half0: k0+6, half1: k0+7
            const float4 pan1 = LD4(i1, gp);     // uniform per half
            const float4 pan2 = LD4(i2, gp);
            float4 v1 = LD4(i1, gg);
            float4 v2 = LD4(i2, gg);
            SWEEP4(v1, pan1)
            SWEEP4(v2, pan2)
            // ---- cross-half exchange: all lanes get all 4 pivot rows
            const float4 o1 = swap32(v1);
            const float4 o2 = swap32(v2);
            float4 P0 = h ? o1 : v1;             // row k0+4
            float4 P1 = h ? v1 : o1;             // row k0+5
            float4 P2 = h ? o2 : v2;             // row k0+6
            float4 P3 = h ? v2 : o2;             // row k0+7
            // ---- pp = panel column group gp+1, via readlane (uniform lane)
            const int gq = gp + 1;
            float4 pp0 = make_float4(rdl(P0.x, gq), rdl(P0.y, gq), rdl(P0.z, gq), rdl(P0.w, gq));
            float4 pp1 = make_float4(rdl(P1.x, gq), rdl(P1.y, gq), rdl(P1.z, gq), rdl(P1.w, gq));
            float4 pp2 = make_float4(rdl(P2.x, gq), rdl(P2.y, gq), rdl(P2.z, gq), rdl(P2.w, gq));
            float4 pp3 = make_float4(rdl(P3.x, gq), rdl(P3.y, gq), rdl(P3.z, gq), rdl(P3.w, gq));
            PANEL_CORE()
            if (g < 25) {
                qbuf[nb][0][g] = Q0; qbuf[nb][1][g] = Q1;
                qbuf[nb][2][g] = Q2; qbuf[nb][3][g] = Q3;
            }
            __builtin_amdgcn_s_setprio(0);
        } else {
            // ---- consumers: fetch Q(k0) (prologue regs at k0==0), bulk sweep
            if (k0 > 0) {
                Q0 = qbuf[b][0][gg]; Q1 = qbuf[b][1][gg];
                Q2 = qbuf[b][2][gg]; Q3 = qbuf[b][3][gg];
            }
            if (g > gp && g < 25) {
                int i = k0 + 8 + (sid - 2);      // 14 streams
                for (; i + 42 < BLK; i += 56) {  // 4-deep pipelined
                    const float4 pa = LD4(i,      gp);
                    const float4 pb = LD4(i + 14, gp);
                    const float4 pc = LD4(i + 28, gp);
                    const float4 pd = LD4(i + 42, gp);
                    float4 va = LD4(i,      g);
                    float4 vb = LD4(i + 14, g);
                    float4 vc = LD4(i + 28, g);
                    float4 vd = LD4(i + 42, g);
                    SWEEP4(va, pa) SWEEP4(vb, pb) SWEEP4(vc, pc) SWEEP4(vd, pd)
                    LD4(i,      g) = va;
                    LD4(i + 14, g) = vb;
                    LD4(i + 28, g) = vc;
                    LD4(i + 42, g) = vd;
                }
                for (; i + 14 < BLK; i += 28) {  // 2-deep
                    const float4 pa = LD4(i,      gp);
                    const float4 pb = LD4(i + 14, gp);
                    float4 va = LD4(i,      g);
                    float4 vb = LD4(i + 14, g);
                    SWEEP4(va, pa) SWEEP4(vb, pb)
                    LD4(i,      g) = va;
                    LD4(i + 14, g) = vb;
                }
                for (; i < BLK; i += 14) {
                    const float4 pa = LD4(i, gp);
                    float4 va = LD4(i, g);
                    SWEEP4(va, pa)
                    LD4(i, g) = va;
                }
            }
        }
        __syncthreads();
    }

    // ---- wave 0 lanes hold the full result redundantly; thread 0 publishes
    if (tid == 0) {
        float ld = logf(mant) + (float)e2 * 0.69314718055994531f;
        if ((lneg & 1) || !isfinite(ld)) ld = __int_as_float(0x7fc00000);  // NaN
        out[1 + f] = ld;
        atomicAdd(out, ld);   // out[0] zeroed via memset before launch; NaN propagates
    }
}

extern "C" void kernel_launch(void* const* d_in, const int* in_sizes, int n_in,
                              void* d_out, int out_size, void* d_ws, size_t ws_size,
                              hipStream_t stream) {
    const float* w = (const float*)d_in[0];   // weights (12800,) f32
    const float* L = (const float*)d_in[1];   // L_kernel (12800,12800) f32
    float* out = (float*)d_out;               // [0]=sum, [1..128]=logdets
    hipMemsetAsync(d_out, 0, sizeof(float), stream);   // zero the atomic accumulator
    lu_logdet_kernel<<<NF, NT, 0, stream>>>(w, L, out);
}